// Round 2
// baseline (440.097 us; speedup 1.0000x reference)
//
#include <hip/hip_runtime.h>
#include <hip/hip_bf16.h>

#define BB 4
#define SS 2048
#define FF 128
#define DD 128
#define HD 512
#define OUTD 128
#define BH 16
#define NSL 0.01f
#define NC 258      // prefix columns: 128 (u*hp) + 128 (v*hp) + Su + Sv
#define NCH 128     // chunks of 16 ranks
#define CHK 16

typedef __hip_bfloat16 bf16;
typedef short bf16x8 __attribute__((ext_vector_type(8)));
typedef float f32x4 __attribute__((ext_vector_type(4)));

// ---------------- workspace layout (in floats), total ~72.4 MB ----------------
constexpr size_t OFF_HPF = 0;                                   // hp f32 [B*S][512]
constexpr size_t OFF_E1  = OFF_HPF + (size_t)BB*SS*HD;          // [bh][S]
constexpr size_t OFF_E2  = OFF_E1 + (size_t)BH*SS;
constexpr size_t OFF_M2  = OFF_E2 + (size_t)BH*SS;              // [bh] (padded 64)
constexpr size_t OFF_U   = OFF_M2 + 64;
constexpr size_t OFF_V   = OFF_U + (size_t)BH*SS;
constexpr size_t OFF_DS  = OFF_V + (size_t)BH*SS;               // sorted delta
constexpr size_t OFF_SIG = OFF_DS + (size_t)BH*SS;              // perm (int)
constexpr size_t OFF_PL  = OFF_SIG + (size_t)BH*SS;             // [bh][2049][NC] chunk-local prefix
constexpr size_t OFF_CS  = OFF_PL + (size_t)BH*2049*NC;         // [bh][NCH][NC] chunk sums
constexpr size_t OFF_O   = OFF_CS + (size_t)BH*NCH*NC;          // [bh][NCH][NC] chunk offsets
constexpr size_t OFF_TOT = OFF_O + (size_t)BH*NCH*NC;           // [bh][NC] totals
constexpr size_t OFF_CTX = OFF_TOT + (size_t)BH*NC;             // ctx f32 [B*S][512]

// split f32 x8 into hi/lo bf16 fragments (hi = rne(x), lo = rne(x - hi))
__device__ inline void load8_split(const float* __restrict__ p, bf16x8& hi, bf16x8& lo) {
  f32x4 x0 = *(const f32x4*)p;
  f32x4 x1 = *(const f32x4*)(p + 4);
#pragma unroll
  for (int e = 0; e < 8; ++e) {
    float x = (e < 4) ? x0[e] : x1[e - 4];
    __hip_bfloat16 hb = __float2bfloat16(x);
    float hf = __bfloat162float(hb);
    __hip_bfloat16 lb = __float2bfloat16(x - hf);
    hi[e] = (short)__bfloat16_as_ushort(hb);
    lo[e] = (short)__bfloat16_as_ushort(lb);
  }
}

// K1: hp = h @ W_w^T (+W_b). 16x16 wave tiles, hi/lo-split bf16 MFMA (~f32 accuracy).
__global__ __launch_bounds__(256) void k1_hp(const float* __restrict__ h, const float* __restrict__ Ww,
                                             const float* __restrict__ Wb, float* __restrict__ hpf) {
  int wid = threadIdx.x >> 6, lane = threadIdx.x & 63;
  int tile = blockIdx.x * 4 + wid;          // 16384 tiles = 512 x 32
  int mt = tile >> 5, nt = tile & 31;
  int s0 = mt * 16, n0 = nt * 16;
  int row = lane & 15, g = lane >> 4;
  const float* pa = h  + (size_t)(s0 + row) * FF + g * 8;
  const float* pb = Ww + (size_t)(n0 + row) * FF + g * 8;
  f32x4 acc = {0.f,0.f,0.f,0.f};
#pragma unroll
  for (int ks = 0; ks < 4; ++ks) {
    bf16x8 ah, al, bh_, bl;
    load8_split(pa + ks*32, ah, al);
    load8_split(pb + ks*32, bh_, bl);
    acc = __builtin_amdgcn_mfma_f32_16x16x32_bf16(ah, bh_, acc, 0, 0, 0);
    acc = __builtin_amdgcn_mfma_f32_16x16x32_bf16(ah, bl,  acc, 0, 0, 0);
    acc = __builtin_amdgcn_mfma_f32_16x16x32_bf16(al, bh_, acc, 0, 0, 0);
  }
  int col = lane & 15;
  float bias = Wb[n0 + col];
#pragma unroll
  for (int r = 0; r < 4; ++r) {
    int orow = g*4 + r;   // verified C/D layout: col=lane&15, row=4*(lane>>4)+reg
    hpf[(size_t)(s0 + orow) * HD + n0 + col] = acc[r] + bias;
  }
}

// K2: e1,e2 per (bh,s): wave dot over 128 dims, pure f32
__global__ __launch_bounds__(256) void k2_e(const float* __restrict__ hpf, const float* __restrict__ aw,
                                            float* __restrict__ e1, float* __restrict__ e2) {
  int wid = threadIdx.x >> 6, lane = threadIdx.x & 63;
  int gw = blockIdx.x * 4 + wid;     // 32768 waves
  int bh = gw >> 11, s = gw & 2047;
  int b = bh >> 2, hh = bh & 3;
  const float* rowp = hpf + (size_t)(b*SS + s) * HD + hh * DD;
  float a1a = aw[lane],      a1b = aw[lane + 64];
  float a2a = aw[DD + lane], a2b = aw[DD + lane + 64];
  float xa = rowp[lane], xb = rowp[lane + 64];
  float r1 = xa*a1a + xb*a1b;
  float r2 = xa*a2a + xb*a2b;
  for (int o = 32; o; o >>= 1) { r1 += __shfl_down(r1, o); r2 += __shfl_down(r2, o); }
  if (lane == 0) { e1[(size_t)bh*SS + s] = r1; e2[(size_t)bh*SS + s] = r2; }
}

// K2b: per bh: m2 = max over unmasked e2; u = exp(e2-m2), v = exp(0.01*(e2-m2)); 0 if masked
__global__ __launch_bounds__(256) void k2b_uv(const float* __restrict__ e2, const int* __restrict__ mask,
                                              float* __restrict__ m2out, float* __restrict__ u, float* __restrict__ v) {
  int bh = blockIdx.x; int b = bh >> 2;
  __shared__ float red[256];
  float mx = -1e30f;
  for (int j = threadIdx.x; j < SS; j += 256) {
    float val = e2[(size_t)bh*SS + j];
    if (!mask[b*SS + j]) mx = fmaxf(mx, val);
  }
  red[threadIdx.x] = mx; __syncthreads();
  for (int st = 128; st; st >>= 1) {
    if (threadIdx.x < st) red[threadIdx.x] = fmaxf(red[threadIdx.x], red[threadIdx.x + st]);
    __syncthreads();
  }
  float m2 = red[0];
  if (threadIdx.x == 0) m2out[bh] = m2;
  for (int j = threadIdx.x; j < SS; j += 256) {
    float d = e2[(size_t)bh*SS + j] - m2;
    int mk = mask[b*SS + j];
    u[(size_t)bh*SS + j] = mk ? 0.f : expf(d);
    v[(size_t)bh*SS + j] = mk ? 0.f : expf(NSL * d);
  }
}

// K2c: bitonic sort delta = e2 - m2 (ascending) with permutation, per bh
__global__ __launch_bounds__(1024) void k2c_sort(const float* __restrict__ e2, const float* __restrict__ m2,
                                                 float* __restrict__ dso, int* __restrict__ sig) {
  int bh = blockIdx.x;
  __shared__ float val[SS];
  __shared__ int idx[SS];
  float mm = m2[bh];
  for (int j = threadIdx.x; j < SS; j += 1024) { val[j] = e2[(size_t)bh*SS + j] - mm; idx[j] = j; }
  __syncthreads();
  for (int k = 2; k <= SS; k <<= 1) {
    for (int jj = k >> 1; jj > 0; jj >>= 1) {
      for (int i = threadIdx.x; i < SS; i += 1024) {
        int l = i ^ jj;
        if (l > i) {
          bool up = ((i & k) == 0);
          float vi = val[i], vl = val[l];
          if ((vi > vl) == up) {
            val[i] = vl; val[l] = vi;
            int t = idx[i]; idx[i] = idx[l]; idx[l] = t;
          }
        }
      }
      __syncthreads();
    }
  }
  for (int j = threadIdx.x; j < SS; j += 1024) {
    dso[(size_t)bh*SS + j] = val[j];
    sig[(size_t)bh*SS + j] = idx[j];
  }
}

// K3a: chunk-local prefix sums over sorted ranks. cols: [0,128)=u*hp, [128,256)=v*hp, 256=Su, 257=Sv
__global__ __launch_bounds__(320) void k3a_prefix(const float* __restrict__ hpf, const float* __restrict__ u,
                                                  const float* __restrict__ v, const int* __restrict__ sig,
                                                  float* __restrict__ PL, float* __restrict__ CS) {
  int bh = blockIdx.x >> 7;
  int ch = blockIdx.x & (NCH - 1);
  int c = threadIdx.x;
  if (c >= NC) return;
  int b = bh >> 2, hh = bh & 3;
  if (ch == 0) PL[((size_t)bh*2049 + 0)*NC + c] = 0.f;   // rank-0 prefix = 0
  float acc = 0.f;
  int r0 = ch * CHK;
  for (int r = r0; r < r0 + CHK; ++r) {
    int j = sig[(size_t)bh*SS + r];
    float term;
    if (c < 128)      term = u[(size_t)bh*SS + j] * hpf[(size_t)(b*SS + j)*HD + hh*DD + c];
    else if (c < 256) term = v[(size_t)bh*SS + j] * hpf[(size_t)(b*SS + j)*HD + hh*DD + (c-128)];
    else if (c == 256) term = u[(size_t)bh*SS + j];
    else              term = v[(size_t)bh*SS + j];
    acc += term;
    PL[((size_t)bh*2049 + r + 1)*NC + c] = acc;
  }
  CS[((size_t)bh*NCH + ch)*NC + c] = acc;
}

// K3b: exclusive scan of chunk sums -> offsets, and totals
__global__ __launch_bounds__(320) void k3b_scan(const float* __restrict__ CS, float* __restrict__ O,
                                                float* __restrict__ Tot) {
  int bh = blockIdx.x; int c = threadIdx.x;
  if (c >= NC) return;
  float acc = 0.f;
  for (int ch = 0; ch < NCH; ++ch) {
    O[((size_t)bh*NCH + ch)*NC + c] = acc;
    acc += CS[((size_t)bh*NCH + ch)*NC + c];
  }
  Tot[(size_t)bh*NC + c] = acc;
}

// K4: per row i: binary-search crossover rank, denom, ctx from prefix lookups, stream attn row (f32)
__global__ __launch_bounds__(256) void k4_main(const float* __restrict__ e1, const float* __restrict__ m2arr,
                                               const float* __restrict__ u, const float* __restrict__ v,
                                               const float* __restrict__ dso,
                                               const float* __restrict__ PL, const float* __restrict__ O,
                                               const float* __restrict__ Tot,
                                               const float* __restrict__ abp,
                                               float* __restrict__ ctx, float* __restrict__ attn) {
  int bh = blockIdx.x >> 6;      // 64 i-blocks of 32 rows
  int ib = blockIdx.x & 63;
  int b = bh >> 2, hh = bh & 3;
  __shared__ float ds_s[SS];
  __shared__ float u_s[SS];
  __shared__ float v_s[SS];
  for (int j = threadIdx.x; j < SS; j += 256) {
    ds_s[j] = dso[(size_t)bh*SS + j];
    u_s[j]  = u[(size_t)bh*SS + j];
    v_s[j]  = v[(size_t)bh*SS + j];
  }
  __syncthreads();
  int wid = threadIdx.x >> 6, lane = threadIdx.x & 63;
  float m2 = m2arr[bh];
  float ab = abp[0];
  const float* TotRow = Tot + (size_t)bh*NC;
  float SuT = TotRow[256];
  for (int rr = wid; rr < 32; rr += 4) {
    int i = ib*32 + rr;
    float t = e1[(size_t)bh*SS + i] + ab + m2;
    float rm = t > 0.f ? t : NSL*t;             // = leakyrelu(t) = exact row max
    float alpha = expf(t - rm);
    float beta  = expf(NSL*t - rm);
    float tau = -t;
    // lower_bound: first sorted rank with delta >= tau
    int lo = 0, hi = SS;
    while (lo < hi) { int mid = (lo + hi) >> 1; if (ds_s[mid] < tau) lo = mid + 1; else hi = mid; }
    int r = lo;
    int ch = (r == 0) ? 0 : ((r - 1) >> 4);
    const float* PLrow = PL + ((size_t)bh*2049 + r)*NC;
    const float* Orow  = O  + ((size_t)bh*NCH + ch)*NC;
    float SU = PLrow[256] + Orow[256];
    float SV = PLrow[257] + Orow[257];
    float denom = alpha * (SuT - SU) + beta * SV;
    float inv = 1.f / denom;
    float ad = alpha * inv, bd = beta * inv;
    // ctx from prefix lookups
#pragma unroll
    for (int d0 = 0; d0 < 2; ++d0) {
      int d = lane + 64*d0;
      float fu = PLrow[d]       + Orow[d];
      float fv = PLrow[128 + d] + Orow[128 + d];
      float cv = (alpha * (TotRow[d] - fu) + beta * fv) * inv;
      ctx[(size_t)(b*SS + i)*HD + hh*DD + d] = cv;
    }
    float utau = expf(tau);      // piece predicate: u_j >= utau  <=>  delta_j >= tau (monotone)
    float* orow = attn + ((size_t)bh*SS + i)*SS;
#pragma unroll 2
    for (int it = 0; it < 8; ++it) {
      int j0 = it*256 + lane*4;
      f32x4 uu = *(const f32x4*)&u_s[j0];
      f32x4 vv = *(const f32x4*)&v_s[j0];
      f32x4 av;
#pragma unroll
      for (int e = 0; e < 4; ++e) av[e] = (uu[e] >= utau) ? ad*uu[e] : bd*vv[e];
      *(f32x4*)(orow + j0) = av;
    }
  }
}

// K5: out = relu(ctx @ out_w^T + out_b), hi/lo-split bf16 MFMA (~f32 accuracy)
__global__ __launch_bounds__(256) void k5_out(const float* __restrict__ ctx, const float* __restrict__ W2,
                                              const float* __restrict__ b2, float* __restrict__ outp) {
  int wid = threadIdx.x >> 6, lane = threadIdx.x & 63;
  int s0 = blockIdx.x * 16;        // 512 blocks
  int n0 = wid * 32;
  int row = lane & 15, g = lane >> 4;
  const float* pa  = ctx + (size_t)(s0 + row) * HD + g * 8;
  const float* pb0 = W2  + (size_t)(n0 + row) * HD + g * 8;
  const float* pb1 = W2  + (size_t)(n0 + 16 + row) * HD + g * 8;
  f32x4 acc0 = {0.f,0.f,0.f,0.f}, acc1 = {0.f,0.f,0.f,0.f};
  for (int ks = 0; ks < 16; ++ks) {
    bf16x8 ah, al, b0h, b0l, b1h, b1l;
    load8_split(pa  + ks*32, ah,  al);
    load8_split(pb0 + ks*32, b0h, b0l);
    load8_split(pb1 + ks*32, b1h, b1l);
    acc0 = __builtin_amdgcn_mfma_f32_16x16x32_bf16(ah, b0h, acc0, 0,0,0);
    acc0 = __builtin_amdgcn_mfma_f32_16x16x32_bf16(ah, b0l, acc0, 0,0,0);
    acc0 = __builtin_amdgcn_mfma_f32_16x16x32_bf16(al, b0h, acc0, 0,0,0);
    acc1 = __builtin_amdgcn_mfma_f32_16x16x32_bf16(ah, b1h, acc1, 0,0,0);
    acc1 = __builtin_amdgcn_mfma_f32_16x16x32_bf16(ah, b1l, acc1, 0,0,0);
    acc1 = __builtin_amdgcn_mfma_f32_16x16x32_bf16(al, b1h, acc1, 0,0,0);
  }
  int col = lane & 15;
  float bias0 = b2[n0 + col];
  float bias1 = b2[n0 + 16 + col];
#pragma unroll
  for (int r2 = 0; r2 < 4; ++r2) {
    int orow = g*4 + r2;
    float v0 = acc0[r2] + bias0; v0 = v0 > 0.f ? v0 : 0.f;
    float v1 = acc1[r2] + bias1; v1 = v1 > 0.f ? v1 : 0.f;
    outp[(size_t)(s0 + orow)*OUTD + n0 + col]      = v0;
    outp[(size_t)(s0 + orow)*OUTD + n0 + 16 + col] = v1;
  }
}

extern "C" void kernel_launch(void* const* d_in, const int* in_sizes, int n_in,
                              void* d_out, int out_size, void* d_ws, size_t ws_size,
                              hipStream_t stream) {
  const float* h   = (const float*)d_in[0];
  const int* mask  = (const int*)d_in[1];
  const float* Ww  = (const float*)d_in[2];
  const float* Wb  = (const float*)d_in[3];
  const float* aw  = (const float*)d_in[4];
  const float* abp = (const float*)d_in[5];
  const float* W2  = (const float*)d_in[6];
  const float* b2  = (const float*)d_in[7];
  float* ws = (float*)d_ws;
  float* hpf = ws + OFF_HPF;
  float* e1  = ws + OFF_E1;
  float* e2  = ws + OFF_E2;
  float* m2  = ws + OFF_M2;
  float* u   = ws + OFF_U;
  float* v   = ws + OFF_V;
  float* dso = ws + OFF_DS;
  int*   sig = (int*)(ws + OFF_SIG);
  float* PL  = ws + OFF_PL;
  float* CS  = ws + OFF_CS;
  float* O   = ws + OFF_O;
  float* Tot = ws + OFF_TOT;
  float* ctx = ws + OFF_CTX;
  float* outp = (float*)d_out;
  float* attn = outp + (size_t)BB*SS*OUTD;

  k1_hp<<<4096, 256, 0, stream>>>(h, Ww, Wb, hpf);
  k2_e<<<8192, 256, 0, stream>>>(hpf, aw, e1, e2);
  k2b_uv<<<16, 256, 0, stream>>>(e2, mask, m2, u, v);
  k2c_sort<<<16, 1024, 0, stream>>>(e2, m2, dso, sig);
  k3a_prefix<<<BH*NCH, 320, 0, stream>>>(hpf, u, v, sig, PL, CS);
  k3b_scan<<<16, 320, 0, stream>>>(CS, O, Tot);
  k4_main<<<BH*64, 256, 0, stream>>>(e1, m2, u, v, dso, PL, O, Tot, abp, ctx, attn);
  k5_out<<<512, 256, 0, stream>>>(ctx, W2, b2, outp);
}